// Round 5
// baseline (307.202 us; speedup 1.0000x reference)
//
#include <hip/hip_runtime.h>

// ============================================================================
// QuantumHeadAmplitude — R5 (= R4 + S6 cover fix): fully fused single-kernel
// simulator. One block (1024 thr) = one batch element; 65536 amps live in
// registers (64 packed-fp16 amps/thread) + 128 KB LDS as the exchange medium.
// CNOTs virtualized via GF(2) index maps (validated R1-R3). 6 register
// stages / 5 LDS bit-exchanges cover all 32 Rot gates; expvals + linear
// head fused. HBM traffic: read x once, write 2560 floats.
//
// R4 bug: l1mask[15] = b0^b14^b15 (CNOT(15,0) hits the already-updated
// col[0]) — S6 reg set now {0,1,2,3,14,15}; tg6 remapped (t9->g10 kept).
// ============================================================================

#define BATCH 256
#define NCLS 10

typedef float v2f __attribute__((ext_vector_type(2)));
typedef _Float16 f16x2 __attribute__((ext_vector_type(2)));

struct CircuitMeta { unsigned l1mask[16]; unsigned l1role[16]; unsigned fin[16]; };

__host__ __device__ constexpr CircuitMeta make_meta() {
  CircuitMeta m{};
  unsigned col[16] = {}, inv[16] = {};
  for (int w = 0; w < 16; ++w) { col[w] = 1u << (15 - w); inv[w] = 1u << (15 - w); }
  for (int w = 0; w < 16; ++w) { int c = w, t = (w + 1) & 15; col[c] ^= col[t]; inv[t] ^= inv[c]; }
  for (int w = 0; w < 16; ++w) { m.l1mask[w] = col[w]; m.l1role[w] = inv[w]; }
  for (int w = 0; w < 16; ++w) { int c = w, t = (w + 2) & 15; col[c] ^= col[t]; inv[t] ^= inv[c]; }
  for (int w = 0; w < 16; ++w) m.fin[w] = inv[w];
  return m;
}
constexpr CircuitMeta META = make_meta();

// 15-bit LDS index hash (invertible; spreads high bits into bank bits)
__host__ __device__ constexpr unsigned XH(unsigned q) {
  return q ^ ((q >> 5) & 31u) ^ ((q >> 10) & 31u);
}
template<int H> __host__ __device__ constexpr unsigned QDROP(unsigned i) {
  return (i & ((1u << H) - 1u)) | ((i >> (H + 1)) << H);
}

// ---- stage thread-bit maps (t -> global bits not in the stage's reg set) ----
__host__ __device__ constexpr unsigned tg1(unsigned t){ return t << 2; }                                       // g2..11
__host__ __device__ constexpr unsigned tg2(unsigned t){ return (t & 63u) | (((t >> 6) & 15u) << 12); }         // g0..5,g12..15 (t9->g15)
__host__ __device__ constexpr unsigned tg3(unsigned t){ return ((t & 31u) << 6) | (((t >> 5) & 15u) << 12) | (((t >> 9) & 1u) << 11); } // g6..10,g12..15,t9->g11
__host__ __device__ constexpr unsigned tg4(unsigned t){ return (t & 31u) | (((t >> 5) & 15u) << 6) | (((t >> 9) & 1u) << 5); }          // g0..4,g6..9,t9->g5
__host__ __device__ constexpr unsigned tg5(unsigned t){ return (t & 31u) | (((t >> 5) & 31u) << 11); }          // g0..4,g11..15
__host__ __device__ constexpr unsigned tg6(unsigned t){ return ((t & 63u) << 4) | (((t >> 6) & 7u) << 11) | (((t >> 9) & 1u) << 10); }  // g4..9,g11..13,t9->g10

// ---- stage reg-bit maps (j bit k -> global bit Bk) ----
template<int B0,int B1,int B2,int B3,int B4,int B5>
__host__ __device__ constexpr unsigned rv6b(unsigned j) {
  return ((j & 1u) << B0) | (((j >> 1) & 1u) << B1) | (((j >> 2) & 1u) << B2) |
         (((j >> 3) & 1u) << B3) | (((j >> 4) & 1u) << B4) | (((j >> 5) & 1u) << B5);
}
__host__ __device__ constexpr unsigned rv_s1(unsigned j){ return rv6b<0,1,12,13,14,15>(j); }
__host__ __device__ constexpr unsigned rv_s2(unsigned j){ return rv6b<6,7,8,9,10,11>(j); }
__host__ __device__ constexpr unsigned rv_s3(unsigned j){ return rv6b<0,1,2,3,4,5>(j); }
__host__ __device__ constexpr unsigned rv_s4(unsigned j){ return rv6b<11,12,13,14,15,10>(j); }
__host__ __device__ constexpr unsigned rv_s5(unsigned j){ return rv6b<5,6,7,8,9,10>(j); }
__host__ __device__ constexpr unsigned rv_s6(unsigned j){ return rv6b<0,1,2,3,14,15>(j); }

__device__ __forceinline__ v2f swp(v2f a) { return __builtin_shufflevector(a, a, 1, 0); }
__device__ __forceinline__ unsigned PK(v2f a) {
  return __builtin_bit_cast(unsigned, __builtin_amdgcn_cvt_pkrtz(a.x, a.y));
}
__device__ __forceinline__ v2f UNPK(unsigned u) {
  f16x2 h = __builtin_bit_cast(f16x2, u);
  return (v2f){(float)h.x, (float)h.y};
}

// Generalized 1q gate over 64 packed amps (6 reg bits at global positions
// B0..B5). MG = XOR mask (static-checked within reg set), RG = role row.
// tp = thread's non-reg global bits. Math in f32 (unpack/compute/pack).
template<int B0,int B1,int B2,int B3,int B4,int B5, unsigned MG, unsigned RG>
__device__ __forceinline__ void gate6(unsigned (&A)[64], const float* __restrict__ g,
                                      int gi, unsigned tp) {
  constexpr unsigned cover = (1u<<B0)|(1u<<B1)|(1u<<B2)|(1u<<B3)|(1u<<B4)|(1u<<B5);
  static_assert((MG & ~cover) == 0u, "gate mask not covered by stage reg bits");
  constexpr unsigned mr = ((MG>>B0)&1u) | (((MG>>B1)&1u)<<1) | (((MG>>B2)&1u)<<2)
                        | (((MG>>B3)&1u)<<3) | (((MG>>B4)&1u)<<4) | (((MG>>B5)&1u)<<5);
  static_assert(mr != 0u, "empty reg mask");
  constexpr unsigned pivot = mr & (0u - mr);

  float u00r = g[gi*8+0], u00i = g[gi*8+1], u01r = g[gi*8+2], u01i = g[gi*8+3];
  float u10r = g[gi*8+4], u10i = g[gi*8+5], u11r = g[gi*8+6], u11i = g[gi*8+7];
  const bool s = (__popc(RG & tp) & 1) != 0;   // thread-part role parity
  float e00r = s ? u11r : u00r, e00i = s ? u11i : u00i;
  float e01r = s ? u10r : u01r, e01i = s ? u10i : u01i;
  float e10r = s ? u01r : u10r, e10i = s ? u01i : u10i;
  float e11r = s ? u00r : u11r, e11i = s ? u00i : u11i;
  v2f a00 = {e00r, e00r}, b00 = {-e00i, e00i};
  v2f a01 = {e01r, e01r}, b01 = {-e01i, e01i};
  v2f a10 = {e10r, e10r}, b10 = {-e10i, e10i};
  v2f a11 = {e11r, e11r}, b11 = {-e11i, e11i};

  #pragma unroll
  for (int j0 = 0; j0 < 64; ++j0) {
    if (j0 & (int)pivot) continue;           // canonical pair rep (folds)
    const int j1 = j0 ^ (int)mr;
    const bool podd =
      (__builtin_popcount(RG & rv6b<B0,B1,B2,B3,B4,B5>((unsigned)j0)) & 1) != 0; // folds
    v2f v0 = UNPK(A[j0]), v1 = UNPK(A[j1]);
    v2f v0s = swp(v0), v1s = swp(v1);
    if (!podd) {
      A[j0] = PK(a00*v0 + b00*v0s + a01*v1 + b01*v1s);
      A[j1] = PK(a10*v0 + b10*v0s + a11*v1 + b11*v1s);
    } else {
      A[j0] = PK(a11*v0 + b11*v0s + a10*v1 + b10*v1s);
      A[j1] = PK(a01*v0 + b01*v0s + a00*v1 + b00*v1s);
    }
  }
}

// Rot(phi,theta,omega) = RZ(omega) RY(theta) RZ(phi) -> 32 gates x 8 floats
__global__ void prep_gates(const float* __restrict__ qp, float* __restrict__ g) {
  int i = threadIdx.x;
  if (i >= 32) return;
  float phi = qp[i*3+0], th = qp[i*3+1], om = qp[i*3+2];
  float cth = cosf(0.5f*th), sth = sinf(0.5f*th);
  float a = 0.5f*(phi+om), d = 0.5f*(phi-om);
  float ca = cosf(a), sa = sinf(a), cd = cosf(d), sd = sinf(d);
  g[i*8+0] =  ca*cth; g[i*8+1] = -sa*cth;
  g[i*8+2] = -cd*sth; g[i*8+3] = -sd*sth;
  g[i*8+4] =  cd*sth; g[i*8+5] = -sd*sth;
  g[i*8+6] =  ca*cth; g[i*8+7] =  sa*cth;
}

// Exchange with temp (HH = write-side j5 bit; read side keys on t9->g[HH]):
// round r moves the half-state with g[HH]==r (32768 amps = full 128 KB LDS).
#define EXCH_TMP(HH, TGIN, RVIN, TGOUT, RVOUT)                                   \
  {                                                                              \
    const unsigned qbw = XH(QDROP<HH>(TGIN(t)));                                 \
    const unsigned qbr = XH(QDROP<HH>(TGOUT(t)));                                \
    const bool rlow = ((t >> 9) & 1u) == 0u;                                     \
    _Pragma("unroll")                                                            \
    for (int j = 0; j < 32; ++j) L[qbw ^ XH(QDROP<HH>(RVIN((unsigned)j)))] = A[j]; \
    __syncthreads();                                                             \
    if (rlow) {                                                                  \
      _Pragma("unroll")                                                          \
      for (int j = 0; j < 32; ++j) A[j] = L[qbr ^ XH(QDROP<HH>(RVOUT((unsigned)j)))]; \
      _Pragma("unroll")                                                          \
      for (int j = 0; j < 32; ++j) T[j] = L[qbr ^ XH(QDROP<HH>(RVOUT((unsigned)j + 32u)))]; \
    }                                                                            \
    __syncthreads();                                                             \
    _Pragma("unroll")                                                            \
    for (int j = 32; j < 64; ++j) L[qbw ^ XH(QDROP<HH>(RVIN((unsigned)j)))] = A[j]; \
    __syncthreads();                                                             \
    if (!rlow) {                                                                 \
      _Pragma("unroll")                                                          \
      for (int j = 0; j < 64; ++j) A[j] = L[qbr ^ XH(QDROP<HH>(RVOUT((unsigned)j)))]; \
    } else {                                                                     \
      _Pragma("unroll")                                                          \
      for (int j = 0; j < 32; ++j) A[32 + j] = T[j];                             \
    }                                                                            \
    __syncthreads();                                                             \
  }

// Exchange where g[HH] is reg-bit-5 on BOTH sides: no temp, all lanes active.
#define EXCH_SHR(HH, TGIN, RVIN, TGOUT, RVOUT)                                   \
  {                                                                              \
    const unsigned qbw = XH(QDROP<HH>(TGIN(t)));                                 \
    const unsigned qbr = XH(QDROP<HH>(TGOUT(t)));                                \
    _Pragma("unroll")                                                            \
    for (int j = 0; j < 32; ++j) L[qbw ^ XH(QDROP<HH>(RVIN((unsigned)j)))] = A[j]; \
    __syncthreads();                                                             \
    _Pragma("unroll")                                                            \
    for (int j = 0; j < 32; ++j) A[j] = L[qbr ^ XH(QDROP<HH>(RVOUT((unsigned)j)))]; \
    __syncthreads();                                                             \
    _Pragma("unroll")                                                            \
    for (int j = 32; j < 64; ++j) L[qbw ^ XH(QDROP<HH>(RVIN((unsigned)j)))] = A[j]; \
    __syncthreads();                                                             \
    _Pragma("unroll")                                                            \
    for (int j = 32; j < 64; ++j) A[j] = L[qbr ^ XH(QDROP<HH>(RVOUT((unsigned)j)))]; \
    __syncthreads();                                                             \
  }

__global__ __launch_bounds__(1024, 4) void qsim(
    const float* __restrict__ x, const float* __restrict__ g,
    const float* __restrict__ W, const float* __restrict__ bias,
    float* __restrict__ out)
{
  extern __shared__ unsigned L[];            // 32768 dwords = 128 KB
  const unsigned t = threadIdx.x;
  unsigned A[64];
  unsigned T[32];

  // ---- load x in S1 layout: i = rv_s1(j) | tg1(t); fp32 -> packed fp16 ----
  // j=jh*4+k: k->g0,g1 ; jh->g12..15 ; t->g2..11  => float4 idx (jh<<10)|t
  const float4* xb = (const float4*)(x + ((size_t)blockIdx.x << 16));
  #pragma unroll
  for (int jh = 0; jh < 16; ++jh) {
    float4 v = xb[((unsigned)jh << 10) | t];
    A[jh*4+0] = PK((v2f){v.x, 0.f});
    A[jh*4+1] = PK((v2f){v.y, 0.f});
    A[jh*4+2] = PK((v2f){v.z, 0.f});
    A[jh*4+3] = PK((v2f){v.w, 0.f});
  }

  // ---- S1: reg {0,1,12,13,14,15} — L0 w0..3, w14, w15 ----
  const unsigned tp1 = tg1(t);
  gate6<0,1,12,13,14,15, 0x8000u,0x8000u>(A, g,  0, tp1);
  gate6<0,1,12,13,14,15, 0x4000u,0x4000u>(A, g,  1, tp1);
  gate6<0,1,12,13,14,15, 0x2000u,0x2000u>(A, g,  2, tp1);
  gate6<0,1,12,13,14,15, 0x1000u,0x1000u>(A, g,  3, tp1);
  gate6<0,1,12,13,14,15, 0x0002u,0x0002u>(A, g, 14, tp1);
  gate6<0,1,12,13,14,15, 0x0001u,0x0001u>(A, g, 15, tp1);

  EXCH_TMP(15, tg1, rv_s1, tg2, rv_s2)       // key g15 (S1 j5 / S2 t9)

  // ---- S2: reg {6..11} — L0 w4..9 ----
  const unsigned tp2 = tg2(t);
  gate6<6,7,8,9,10,11, 0x0800u,0x0800u>(A, g, 4, tp2);
  gate6<6,7,8,9,10,11, 0x0400u,0x0400u>(A, g, 5, tp2);
  gate6<6,7,8,9,10,11, 0x0200u,0x0200u>(A, g, 6, tp2);
  gate6<6,7,8,9,10,11, 0x0100u,0x0100u>(A, g, 7, tp2);
  gate6<6,7,8,9,10,11, 0x0080u,0x0080u>(A, g, 8, tp2);
  gate6<6,7,8,9,10,11, 0x0040u,0x0040u>(A, g, 9, tp2);

  EXCH_TMP(11, tg2, rv_s2, tg3, rv_s3)       // key g11 (S2 j5 / S3 t9)

  // ---- S3: reg {0..5} — L0 w10..13, then L1 w10..14 ----
  const unsigned tp3 = tg3(t);
  gate6<0,1,2,3,4,5, 0x0020u,0x0020u>(A, g, 10, tp3);
  gate6<0,1,2,3,4,5, 0x0010u,0x0010u>(A, g, 11, tp3);
  gate6<0,1,2,3,4,5, 0x0008u,0x0008u>(A, g, 12, tp3);
  gate6<0,1,2,3,4,5, 0x0004u,0x0004u>(A, g, 13, tp3);
  gate6<0,1,2,3,4,5, META.l1mask[10], META.l1role[10]>(A, g, 26, tp3);
  gate6<0,1,2,3,4,5, META.l1mask[11], META.l1role[11]>(A, g, 27, tp3);
  gate6<0,1,2,3,4,5, META.l1mask[12], META.l1role[12]>(A, g, 28, tp3);
  gate6<0,1,2,3,4,5, META.l1mask[13], META.l1role[13]>(A, g, 29, tp3);
  gate6<0,1,2,3,4,5, META.l1mask[14], META.l1role[14]>(A, g, 30, tp3);

  EXCH_TMP(5, tg3, rv_s3, tg4, rv_s4)        // key g5 (S3 j5 / S4 t9)

  // ---- S4: reg {10..15} (j5->g10) — L1 w0..4 ----
  const unsigned tp4 = tg4(t);
  gate6<11,12,13,14,15,10, META.l1mask[0], META.l1role[0]>(A, g, 16, tp4);
  gate6<11,12,13,14,15,10, META.l1mask[1], META.l1role[1]>(A, g, 17, tp4);
  gate6<11,12,13,14,15,10, META.l1mask[2], META.l1role[2]>(A, g, 18, tp4);
  gate6<11,12,13,14,15,10, META.l1mask[3], META.l1role[3]>(A, g, 19, tp4);
  gate6<11,12,13,14,15,10, META.l1mask[4], META.l1role[4]>(A, g, 20, tp4);

  EXCH_SHR(10, tg4, rv_s4, tg5, rv_s5)       // key g10 (reg j5 on BOTH sides)

  // ---- S5: reg {5..10} (j5->g10) — L1 w5..9 ----
  const unsigned tp5 = tg5(t);
  gate6<5,6,7,8,9,10, META.l1mask[5], META.l1role[5]>(A, g, 21, tp5);
  gate6<5,6,7,8,9,10, META.l1mask[6], META.l1role[6]>(A, g, 22, tp5);
  gate6<5,6,7,8,9,10, META.l1mask[7], META.l1role[7]>(A, g, 23, tp5);
  gate6<5,6,7,8,9,10, META.l1mask[8], META.l1role[8]>(A, g, 24, tp5);
  gate6<5,6,7,8,9,10, META.l1mask[9], META.l1role[9]>(A, g, 25, tp5);

  EXCH_TMP(10, tg5, rv_s5, tg6, rv_s6)       // key g10 (S5 j5 / S6 t9)

  // ---- S6: reg {0,1,2,3,14,15} — L1 w15 (mask b0^b14^b15 = 0xC001) ----
  const unsigned tp6 = tg6(t);
  gate6<0,1,2,3,14,15, META.l1mask[15], META.l1role[15]>(A, g, 31, tp6);

  // ---- fused Z-expvals ----
  float sv[16], tot = 0.f;
  #pragma unroll
  for (int w = 0; w < 16; ++w) sv[w] = 0.f;
  #pragma unroll
  for (int j = 0; j < 64; ++j) {
    v2f a = UNPK(A[j]);
    const float pr = a.x*a.x + a.y*a.y;
    tot += pr;
    #pragma unroll
    for (int w = 0; w < 16; ++w) {
      const bool neg = (__builtin_popcount(META.fin[w] & rv_s6((unsigned)j)) & 1) != 0; // folds
      sv[w] += neg ? -pr : pr;
    }
  }
  #pragma unroll
  for (int w = 0; w < 16; ++w)
    if (__popc(META.fin[w] & tp6) & 1) sv[w] = -sv[w];     // thread-part sign

  #pragma unroll
  for (int off = 32; off; off >>= 1) {
    tot += __shfl_xor(tot, off, 64);
    #pragma unroll
    for (int w = 0; w < 16; ++w) sv[w] += __shfl_xor(sv[w], off, 64);
  }
  float* RF = (float*)L;                     // LDS reuse (barrier-protected)
  const unsigned wave = t >> 6, lane = t & 63u;
  if (lane == 0) {
    #pragma unroll
    for (int w = 0; w < 16; ++w) RF[wave*17 + w] = sv[w];
    RF[wave*17 + 16] = tot;
  }
  __syncthreads();
  if (t < 17) {
    float s2 = 0.f;
    #pragma unroll
    for (int wv = 0; wv < 16; ++wv) s2 += RF[wv*17 + t];
    RF[272 + t] = s2;
  }
  __syncthreads();
  if (t < NCLS) {
    const float tt = RF[272 + 16];
    float o = bias[t];
    #pragma unroll
    for (int w = 0; w < 16; ++w) o += (RF[272 + w] / tt) * W[t*16 + w];
    out[blockIdx.x * NCLS + t] = o;
  }
}

extern "C" void kernel_launch(void* const* d_in, const int* in_sizes, int n_in,
                              void* d_out, int out_size, void* d_ws, size_t ws_size,
                              hipStream_t stream) {
  (void)in_sizes; (void)n_in; (void)out_size; (void)ws_size;
  const float* x  = (const float*)d_in[0];   // (256, 65536)
  const float* qp = (const float*)d_in[1];   // (2,16,3)
  const float* W  = (const float*)d_in[2];   // (10,16)
  const float* bv = (const float*)d_in[3];   // (10,)
  float* out = (float*)d_out;                // (256,10) fp32

  float* gates = (float*)d_ws;               // 1 KB of ws only

  // 128 KB dynamic LDS (gfx950 has 160 KB/CU); host-side attr set, no stream
  // op -> safe under graph capture; idempotent across calls.
  static_cast<void>(hipFuncSetAttribute(
      reinterpret_cast<const void*>(&qsim),
      hipFuncAttributeMaxDynamicSharedMemorySize, 131072));

  prep_gates<<<dim3(1), dim3(64), 0, stream>>>(qp, gates);
  qsim<<<dim3(BATCH), dim3(1024), 131072, stream>>>(x, gates, (const float*)W,
                                                    (const float*)bv, out);
}

// Round 6
// 227.840 us; speedup vs baseline: 1.3483x; 1.3483x over previous
//
#include <hip/hip_runtime.h>

// ============================================================================
// QuantumHeadAmplitude — R6: fused single-kernel sim, spill-free register plan.
// One block (1024 thr) = one batch element; 64 packed-fp16 amps/thread.
// All 6 stage pairs share a reg bit at the same j-position -> all 5 LDS
// exchanges are 2-round, NO temp array (A[64] only). launch_bounds(1024,1)
// so the VGPR cap is >=128 under either HIP/CUDA arg-2 semantics.
// CNOTs virtualized via GF(2) index maps (validated R1-R5).
// ============================================================================

#define BATCH 256
#define NCLS 10

typedef float v2f __attribute__((ext_vector_type(2)));
typedef _Float16 f16x2 __attribute__((ext_vector_type(2)));

struct CircuitMeta { unsigned l1mask[16]; unsigned l1role[16]; unsigned fin[16]; };

__host__ __device__ constexpr CircuitMeta make_meta() {
  CircuitMeta m{};
  unsigned col[16] = {}, inv[16] = {};
  for (int w = 0; w < 16; ++w) { col[w] = 1u << (15 - w); inv[w] = 1u << (15 - w); }
  for (int w = 0; w < 16; ++w) { int c = w, t = (w + 1) & 15; col[c] ^= col[t]; inv[t] ^= inv[c]; }
  for (int w = 0; w < 16; ++w) { m.l1mask[w] = col[w]; m.l1role[w] = inv[w]; }
  for (int w = 0; w < 16; ++w) { int c = w, t = (w + 2) & 15; col[c] ^= col[t]; inv[t] ^= inv[c]; }
  for (int w = 0; w < 16; ++w) m.fin[w] = inv[w];
  return m;
}
constexpr CircuitMeta META = make_meta();

// 15-bit LDS index hash (GF2-linear; folds bits 5..14 into bank bits 0..4)
__host__ __device__ constexpr unsigned XH(unsigned q) {
  return q ^ ((q >> 5) & 31u) ^ ((q >> 10) & 31u);
}
template<int H> __host__ __device__ constexpr unsigned QDROP(unsigned i) {
  return (i & ((1u << H) - 1u)) | ((i >> (H + 1)) << H);
}

// ---- stage reg-bit maps (j bit k -> global bit Bk) ----
template<int B0,int B1,int B2,int B3,int B4,int B5>
__host__ __device__ constexpr unsigned rv6b(unsigned j) {
  return ((j & 1u) << B0) | (((j >> 1) & 1u) << B1) | (((j >> 2) & 1u) << B2) |
         (((j >> 3) & 1u) << B3) | (((j >> 4) & 1u) << B4) | (((j >> 5) & 1u) << B5);
}
// Key-bit positions: g0@j5 in S1,S2,S5,S6; g11@j0 in S2,S3,S4,S5; g6@j5 in S3,S4.
__host__ __device__ constexpr unsigned rv_s1(unsigned j){ return rv6b<1,12,13,14,15,0>(j); }
__host__ __device__ constexpr unsigned rv_s2(unsigned j){ return rv6b<11,7,8,9,10,0>(j); }
__host__ __device__ constexpr unsigned rv_s3(unsigned j){ return rv6b<11,2,3,4,5,6>(j); }
__host__ __device__ constexpr unsigned rv_s4(unsigned j){ return rv6b<11,7,8,9,10,6>(j); }
__host__ __device__ constexpr unsigned rv_s5(unsigned j){ return rv6b<11,12,13,14,15,0>(j); }
__host__ __device__ constexpr unsigned rv_s6(unsigned j){ return rv6b<1,2,3,4,5,0>(j); }

// ---- stage thread-bit maps (t0..t9 -> complement of the stage's reg set) ----
__host__ __device__ constexpr unsigned tg1(unsigned t){ return t << 2; }                                              // g2..11
__host__ __device__ constexpr unsigned tg2(unsigned t){ return ((t & 63u) << 1) | ((t >> 6) << 12); }                 // g1..6, g12..15
__host__ __device__ constexpr unsigned tg3(unsigned t){ return (t & 3u) | (((t >> 2) & 15u) << 7) | ((t >> 6) << 12); } // g0,1, g7..10, g12..15
__host__ __device__ constexpr unsigned tg4(unsigned t){ return (t & 63u) | ((t >> 6) << 12); }                        // g0..5, g12..15
__host__ __device__ constexpr unsigned tg5(unsigned t){ return t << 1; }                                              // g1..10
__host__ __device__ constexpr unsigned tg6(unsigned t){ return t << 6; }                                              // g6..15

__device__ __forceinline__ v2f swp(v2f a) { return __builtin_shufflevector(a, a, 1, 0); }
__device__ __forceinline__ unsigned PK(v2f a) {
  return __builtin_bit_cast(unsigned, __builtin_amdgcn_cvt_pkrtz(a.x, a.y));
}
__device__ __forceinline__ v2f UNPK(unsigned u) {
  f16x2 h = __builtin_bit_cast(f16x2, u);
  return (v2f){(float)h.x, (float)h.y};
}

// Generalized 1q gate over 64 packed amps (6 reg bits at global positions
// B0..B5). MG = XOR mask (static-checked), RG = role row. tp = thread's
// non-reg global bits. Role parity = parity(RG&tp) [hoisted U-vs-XUX select]
// ^ parity(RG&rv(j)) [compile-time].
template<int B0,int B1,int B2,int B3,int B4,int B5, unsigned MG, unsigned RG>
__device__ __forceinline__ void gate6(unsigned (&A)[64], const float* __restrict__ g,
                                      int gi, unsigned tp) {
  constexpr unsigned cover = (1u<<B0)|(1u<<B1)|(1u<<B2)|(1u<<B3)|(1u<<B4)|(1u<<B5);
  static_assert((MG & ~cover) == 0u, "gate mask not covered by stage reg bits");
  constexpr unsigned mr = ((MG>>B0)&1u) | (((MG>>B1)&1u)<<1) | (((MG>>B2)&1u)<<2)
                        | (((MG>>B3)&1u)<<3) | (((MG>>B4)&1u)<<4) | (((MG>>B5)&1u)<<5);
  static_assert(mr != 0u, "empty reg mask");
  constexpr unsigned pivot = mr & (0u - mr);

  float u00r = g[gi*8+0], u00i = g[gi*8+1], u01r = g[gi*8+2], u01i = g[gi*8+3];
  float u10r = g[gi*8+4], u10i = g[gi*8+5], u11r = g[gi*8+6], u11i = g[gi*8+7];
  const bool s = (__popc(RG & tp) & 1) != 0;
  float e00r = s ? u11r : u00r, e00i = s ? u11i : u00i;
  float e01r = s ? u10r : u01r, e01i = s ? u10i : u01i;
  float e10r = s ? u01r : u10r, e10i = s ? u01i : u10i;
  float e11r = s ? u00r : u11r, e11i = s ? u00i : u11i;
  v2f a00 = {e00r, e00r}, b00 = {-e00i, e00i};
  v2f a01 = {e01r, e01r}, b01 = {-e01i, e01i};
  v2f a10 = {e10r, e10r}, b10 = {-e10i, e10i};
  v2f a11 = {e11r, e11r}, b11 = {-e11i, e11i};

  #pragma unroll
  for (int j0 = 0; j0 < 64; ++j0) {
    if (j0 & (int)pivot) continue;           // canonical pair rep (folds)
    const int j1 = j0 ^ (int)mr;
    const bool podd =
      (__builtin_popcount(RG & rv6b<B0,B1,B2,B3,B4,B5>((unsigned)j0)) & 1) != 0; // folds
    v2f v0 = UNPK(A[j0]), v1 = UNPK(A[j1]);
    v2f v0s = swp(v0), v1s = swp(v1);
    if (!podd) {
      A[j0] = PK(a00*v0 + b00*v0s + a01*v1 + b01*v1s);
      A[j1] = PK(a10*v0 + b10*v0s + a11*v1 + b11*v1s);
    } else {
      A[j0] = PK(a11*v0 + b11*v0s + a10*v1 + b10*v1s);
      A[j1] = PK(a01*v0 + b01*v0s + a00*v1 + b00*v1s);
    }
  }
}

// 2-round, temp-free LDS exchange. Requires: key bit KG is a reg bit at the
// SAME j-position in RIN and ROUT (no slot clobber across rounds), and KG not
// in either tg map. Round r moves amps with g[KG]==r (32768 amps = 128 KB).
using RVF = unsigned(*)(unsigned);
template<int KG, RVF RIN, RVF ROUT>
__device__ __forceinline__ void exch(unsigned (&A)[64], unsigned* L,
                                     unsigned tin, unsigned tout) {
  const unsigned qbw = XH(QDROP<KG>(tin));
  const unsigned qbr = XH(QDROP<KG>(tout));
  #pragma unroll
  for (int r = 0; r < 2; ++r) {
    #pragma unroll
    for (int j = 0; j < 64; ++j)
      if (((RIN((unsigned)j) >> KG) & 1u) == (unsigned)r)
        L[qbw ^ XH(QDROP<KG>(RIN((unsigned)j)))] = A[j];
    __syncthreads();
    #pragma unroll
    for (int j = 0; j < 64; ++j)
      if (((ROUT((unsigned)j) >> KG) & 1u) == (unsigned)r)
        A[j] = L[qbr ^ XH(QDROP<KG>(ROUT((unsigned)j)))];
    __syncthreads();
  }
}

// Rot(phi,theta,omega) = RZ(omega) RY(theta) RZ(phi) -> 32 gates x 8 floats
__global__ void prep_gates(const float* __restrict__ qp, float* __restrict__ g) {
  int i = threadIdx.x;
  if (i >= 32) return;
  float phi = qp[i*3+0], th = qp[i*3+1], om = qp[i*3+2];
  float cth = cosf(0.5f*th), sth = sinf(0.5f*th);
  float a = 0.5f*(phi+om), d = 0.5f*(phi-om);
  float ca = cosf(a), sa = sinf(a), cd = cosf(d), sd = sinf(d);
  g[i*8+0] =  ca*cth; g[i*8+1] = -sa*cth;
  g[i*8+2] = -cd*sth; g[i*8+3] = -sd*sth;
  g[i*8+4] =  cd*sth; g[i*8+5] = -sd*sth;
  g[i*8+6] =  ca*cth; g[i*8+7] =  sa*cth;
}

__global__ __launch_bounds__(1024, 1) void qsim(
    const float* __restrict__ x, const float* __restrict__ g,
    const float* __restrict__ W, const float* __restrict__ bias,
    float* __restrict__ out)
{
  extern __shared__ unsigned L[];            // 32768 dwords = 128 KB
  const unsigned t = threadIdx.x;
  unsigned A[64];

  // ---- load x in S1 layout: i = rv_s1(j)|tg1(t) -> float4 idx = t|(jh<<10),
  // j = j0 | (jh<<1) | (j5<<5), (g1,g0) = (j0, j5) = i bits (1,0) ----
  const float4* xb = (const float4*)(x + ((size_t)blockIdx.x << 16));
  #pragma unroll
  for (int jh = 0; jh < 16; ++jh) {
    float4 v = xb[(unsigned)t | ((unsigned)jh << 10)];
    A[(jh << 1) +  0] = PK((v2f){v.x, 0.f});   // g1=0 g0=0
    A[(jh << 1) + 32] = PK((v2f){v.y, 0.f});   // g1=0 g0=1
    A[(jh << 1) +  1] = PK((v2f){v.z, 0.f});   // g1=1 g0=0
    A[(jh << 1) + 33] = PK((v2f){v.w, 0.f});   // g1=1 g0=1
  }

  // ---- S1: regs {1,12,13,14,15,0} — L0 w0..3, w14, w15 ----
  const unsigned tp1 = tg1(t);
  gate6<1,12,13,14,15,0, 0x8000u,0x8000u>(A, g,  0, tp1);
  gate6<1,12,13,14,15,0, 0x4000u,0x4000u>(A, g,  1, tp1);
  gate6<1,12,13,14,15,0, 0x2000u,0x2000u>(A, g,  2, tp1);
  gate6<1,12,13,14,15,0, 0x1000u,0x1000u>(A, g,  3, tp1);
  gate6<1,12,13,14,15,0, 0x0002u,0x0002u>(A, g, 14, tp1);
  gate6<1,12,13,14,15,0, 0x0001u,0x0001u>(A, g, 15, tp1);

  exch<0, rv_s1, rv_s2>(A, L, tp1, tg2(t));  // key g0 (j5 both sides)

  // ---- S2: regs {11,7,8,9,10,0} — L0 w4..8 ----
  const unsigned tp2 = tg2(t);
  gate6<11,7,8,9,10,0, 0x0800u,0x0800u>(A, g, 4, tp2);
  gate6<11,7,8,9,10,0, 0x0400u,0x0400u>(A, g, 5, tp2);
  gate6<11,7,8,9,10,0, 0x0200u,0x0200u>(A, g, 6, tp2);
  gate6<11,7,8,9,10,0, 0x0100u,0x0100u>(A, g, 7, tp2);
  gate6<11,7,8,9,10,0, 0x0080u,0x0080u>(A, g, 8, tp2);

  exch<11, rv_s2, rv_s3>(A, L, tp2, tg3(t)); // key g11 (j0 both sides)

  // ---- S3: regs {11,2,3,4,5,6} — L0 w9..13, then L1 w9..12 ----
  const unsigned tp3 = tg3(t);
  gate6<11,2,3,4,5,6, 0x0040u,0x0040u>(A, g,  9, tp3);
  gate6<11,2,3,4,5,6, 0x0020u,0x0020u>(A, g, 10, tp3);
  gate6<11,2,3,4,5,6, 0x0010u,0x0010u>(A, g, 11, tp3);
  gate6<11,2,3,4,5,6, 0x0008u,0x0008u>(A, g, 12, tp3);
  gate6<11,2,3,4,5,6, 0x0004u,0x0004u>(A, g, 13, tp3);
  gate6<11,2,3,4,5,6, META.l1mask[ 9], META.l1role[ 9]>(A, g, 25, tp3);
  gate6<11,2,3,4,5,6, META.l1mask[10], META.l1role[10]>(A, g, 26, tp3);
  gate6<11,2,3,4,5,6, META.l1mask[11], META.l1role[11]>(A, g, 27, tp3);
  gate6<11,2,3,4,5,6, META.l1mask[12], META.l1role[12]>(A, g, 28, tp3);

  exch<6, rv_s3, rv_s4>(A, L, tp3, tg4(t));  // key g6 (j5 both sides)

  // ---- S4: regs {11,7,8,9,10,6} — L1 w4..8 ----
  const unsigned tp4 = tg4(t);
  gate6<11,7,8,9,10,6, META.l1mask[4], META.l1role[4]>(A, g, 20, tp4);
  gate6<11,7,8,9,10,6, META.l1mask[5], META.l1role[5]>(A, g, 21, tp4);
  gate6<11,7,8,9,10,6, META.l1mask[6], META.l1role[6]>(A, g, 22, tp4);
  gate6<11,7,8,9,10,6, META.l1mask[7], META.l1role[7]>(A, g, 23, tp4);
  gate6<11,7,8,9,10,6, META.l1mask[8], META.l1role[8]>(A, g, 24, tp4);

  exch<11, rv_s4, rv_s5>(A, L, tp4, tg5(t)); // key g11 (j0 both sides)

  // ---- S5: regs {11,12,13,14,15,0} — L1 w0..3, w15 (mask 0xC001) ----
  const unsigned tp5 = tg5(t);
  gate6<11,12,13,14,15,0, META.l1mask[ 0], META.l1role[ 0]>(A, g, 16, tp5);
  gate6<11,12,13,14,15,0, META.l1mask[ 1], META.l1role[ 1]>(A, g, 17, tp5);
  gate6<11,12,13,14,15,0, META.l1mask[ 2], META.l1role[ 2]>(A, g, 18, tp5);
  gate6<11,12,13,14,15,0, META.l1mask[ 3], META.l1role[ 3]>(A, g, 19, tp5);
  gate6<11,12,13,14,15,0, META.l1mask[15], META.l1role[15]>(A, g, 31, tp5);

  exch<0, rv_s5, rv_s6>(A, L, tp5, tg6(t));  // key g0 (j5 both sides)

  // ---- S6: regs {1,2,3,4,5,0} — L1 w13, w14 ----
  const unsigned tp6 = tg6(t);
  gate6<1,2,3,4,5,0, META.l1mask[13], META.l1role[13]>(A, g, 29, tp6);
  gate6<1,2,3,4,5,0, META.l1mask[14], META.l1role[14]>(A, g, 30, tp6);

  // ---- fused Z-expvals (S6 layout) ----
  float sv[16], tot = 0.f;
  #pragma unroll
  for (int w = 0; w < 16; ++w) sv[w] = 0.f;
  #pragma unroll
  for (int j = 0; j < 64; ++j) {
    v2f a = UNPK(A[j]);
    const float pr = a.x*a.x + a.y*a.y;
    tot += pr;
    #pragma unroll
    for (int w = 0; w < 16; ++w) {
      const bool neg = (__builtin_popcount(META.fin[w] & rv_s6((unsigned)j)) & 1) != 0; // folds
      sv[w] += neg ? -pr : pr;
    }
  }
  #pragma unroll
  for (int w = 0; w < 16; ++w)
    if (__popc(META.fin[w] & tp6) & 1) sv[w] = -sv[w];     // thread-part sign

  #pragma unroll
  for (int off = 32; off; off >>= 1) {
    tot += __shfl_xor(tot, off, 64);
    #pragma unroll
    for (int w = 0; w < 16; ++w) sv[w] += __shfl_xor(sv[w], off, 64);
  }
  float* RF = (float*)L;                     // LDS reuse (barrier-protected)
  const unsigned wave = t >> 6, lane = t & 63u;
  if (lane == 0) {
    #pragma unroll
    for (int w = 0; w < 16; ++w) RF[wave*17 + w] = sv[w];
    RF[wave*17 + 16] = tot;
  }
  __syncthreads();
  if (t < 17) {
    float s2 = 0.f;
    #pragma unroll
    for (int wv = 0; wv < 16; ++wv) s2 += RF[wv*17 + t];
    RF[272 + t] = s2;
  }
  __syncthreads();
  if (t < NCLS) {
    const float tt = RF[272 + 16];
    float o = bias[t];
    #pragma unroll
    for (int w = 0; w < 16; ++w) o += (RF[272 + w] / tt) * W[t*16 + w];
    out[blockIdx.x * NCLS + t] = o;
  }
}

extern "C" void kernel_launch(void* const* d_in, const int* in_sizes, int n_in,
                              void* d_out, int out_size, void* d_ws, size_t ws_size,
                              hipStream_t stream) {
  (void)in_sizes; (void)n_in; (void)out_size; (void)ws_size;
  const float* x  = (const float*)d_in[0];   // (256, 65536)
  const float* qp = (const float*)d_in[1];   // (2,16,3)
  const float* W  = (const float*)d_in[2];   // (10,16)
  const float* bv = (const float*)d_in[3];   // (10,)
  float* out = (float*)d_out;                // (256,10) fp32

  float* gates = (float*)d_ws;               // 1 KB of ws only

  // 128 KB dynamic LDS; host-side attr, idempotent, capture-safe.
  static_cast<void>(hipFuncSetAttribute(
      reinterpret_cast<const void*>(&qsim),
      hipFuncAttributeMaxDynamicSharedMemorySize, 131072));

  prep_gates<<<dim3(1), dim3(64), 0, stream>>>(qp, gates);
  qsim<<<dim3(BATCH), dim3(1024), 131072, stream>>>(x, gates, (const float*)W,
                                                    (const float*)bv, out);
}